// Round 5
// baseline (994.361 us; speedup 1.0000x reference)
//
#include <hip/hip_runtime.h>
#include <hip/hip_bf16.h>
#include <cstdint>

// Problem: B_=2048 windows, N=64 tokens, C=512, H=16 heads, hd=32, nW=64.
// Split pipeline: [k_wprep] -> 2x { k_qkv (GEMM, x+pe fused, d_out as scratch)
//                                   -> k_attn (barrier-free) } -> k_proj.
typedef __bf16 bf16;
typedef __bf16 bf16x8_t __attribute__((ext_vector_type(8)));
typedef __bf16 bf16x4_t __attribute__((ext_vector_type(4)));
typedef float  f32x4_t  __attribute__((ext_vector_type(4)));

#define MFMA16(a, b, c) __builtin_amdgcn_mfma_f32_16x16x32_bf16((a), (b), (c), 0, 0, 0)

// ---------------------------------------------------------------------------
// Kernel 1: convert weights to bf16 (qkv_w 1536x512, proj_w 512x512)
// ---------------------------------------------------------------------------
__global__ void k_wprep(const float* __restrict__ wq, const float* __restrict__ wp,
                        bf16* __restrict__ wqb, bf16* __restrict__ wpb) {
    int t = blockIdx.x * 256 + threadIdx.x;
    int stride = gridDim.x * 256;
    for (int i = t; i < 196608; i += stride) {
        float4 v = ((const float4*)wq)[i];
        bf16x4_t o; o[0]=(bf16)v.x; o[1]=(bf16)v.y; o[2]=(bf16)v.z; o[3]=(bf16)v.w;
        ((bf16x4_t*)wqb)[i] = o;
    }
    for (int i = t; i < 65536; i += stride) {
        float4 v = ((const float4*)wp)[i];
        bf16x4_t o; o[0]=(bf16)v.x; o[1]=(bf16)v.y; o[2]=(bf16)v.z; o[3]=(bf16)v.w;
        ((bf16x4_t*)wpb)[i] = o;
    }
}

// ---------------------------------------------------------------------------
// Kernel 2: QKV GEMM over one M-chunk (65536 rows).
// C[65536,1536] = bf16( (x+pe)[m,:] @ qkv_w^T + qkv_b ).  128x128 tile, BK=64,
// 4 waves, padded LDS (k_proj-proven pattern). x+pe->bf16 fused into A-stage.
// XCD-grouped order: 12 N-blocks of an M-panel contiguous per XCD (A L2 reuse).
// ---------------------------------------------------------------------------
__global__ __launch_bounds__(256, 2) void k_qkv(
    const float* __restrict__ x,     // chunk base: (65536, 512) f32
    const float* __restrict__ pe,    // (64, 512) f32
    const bf16*  __restrict__ Bw,    // (1536, 512) bf16
    const float* __restrict__ bias,  // (1536,) f32
    bf16* __restrict__ Cq)           // chunk out: (65536, 1536) bf16
{
    __shared__ bf16 As[128 * 72];
    __shared__ bf16 Bs[128 * 72];

    const int tid  = threadIdx.x;
    const int lane = tid & 63;
    const int wave = tid >> 6;
    const int lr = lane & 15, lg = lane >> 4;
    const int wr = wave >> 1, wc = wave & 1;
    const int bid = blockIdx.x;                   // 0..6143 (= 8 * 768)
    const int wg  = (bid & 7) * 768 + (bid >> 3); // XCD-contiguous chunks
    const int mb  = wg / 12, nb = wg - mb * 12;   // 512 x 12
    const size_t m0 = (size_t)mb * 128;
    const int n0 = nb * 128;

    f32x4_t acc[4][4] = {};

    for (int kt = 0; kt < 8; ++kt) {
        const int k0 = kt * 64;
        // A: read x f32, add pe, convert -> bf16x8 (small live set)
        bf16x8_t va[4], vb[4];
#pragma unroll
        for (int j = 0; j < 4; ++j) {
            int c = tid + 256 * j;                // 1024 chunks: row=c>>3, i8=(c&7)*8
            int row = c >> 3, i8 = (c & 7) * 8;
            const float* xr = x  + (m0 + row) * 512 + k0 + i8;
            const float* pr = pe + (size_t)(row & 63) * 512 + k0 + i8;  // m0%64==0
            float4 x0 = *(const float4*)(xr);
            float4 x1 = *(const float4*)(xr + 4);
            float4 p0 = *(const float4*)(pr);
            float4 p1 = *(const float4*)(pr + 4);
            bf16x8_t v;
            v[0]=(bf16)(x0.x+p0.x); v[1]=(bf16)(x0.y+p0.y);
            v[2]=(bf16)(x0.z+p0.z); v[3]=(bf16)(x0.w+p0.w);
            v[4]=(bf16)(x1.x+p1.x); v[5]=(bf16)(x1.y+p1.y);
            v[6]=(bf16)(x1.z+p1.z); v[7]=(bf16)(x1.w+p1.w);
            va[j] = v;
            vb[j] = *(const bf16x8_t*)(Bw + (size_t)(n0 + row) * 512 + k0 + i8);
        }
        __syncthreads();
#pragma unroll
        for (int j = 0; j < 4; ++j) {
            int c = tid + 256 * j;
            int row = c >> 3, i8 = (c & 7) * 8;
            *(bf16x8_t*)&As[row * 72 + i8] = va[j];
            *(bf16x8_t*)&Bs[row * 72 + i8] = vb[j];
        }
        __syncthreads();

#pragma unroll
        for (int k2 = 0; k2 < 2; ++k2) {
            bf16x8_t af[4], bfr[4];
#pragma unroll
            for (int i = 0; i < 4; ++i)
                af[i] = *(const bf16x8_t*)&As[(wr * 64 + i * 16 + lr) * 72 + k2 * 32 + lg * 8];
#pragma unroll
            for (int j = 0; j < 4; ++j)
                bfr[j] = *(const bf16x8_t*)&Bs[(wc * 64 + j * 16 + lr) * 72 + k2 * 32 + lg * 8];
#pragma unroll
            for (int i = 0; i < 4; ++i)
#pragma unroll
                for (int j = 0; j < 4; ++j)
                    acc[i][j] = MFMA16(af[i], bfr[j], acc[i][j]);
        }
    }

    float bj[4];
#pragma unroll
    for (int j = 0; j < 4; ++j) bj[j] = bias[n0 + wc * 64 + j * 16 + lr];
#pragma unroll
    for (int i = 0; i < 4; ++i)
#pragma unroll
        for (int j = 0; j < 4; ++j) {
            int col = n0 + wc * 64 + j * 16 + lr;
#pragma unroll
            for (int r = 0; r < 4; ++r) {
                size_t row = m0 + wr * 64 + i * 16 + lg * 4 + r;
                Cq[row * 1536 + col] = (bf16)(acc[i][j][r] + bj[j]);
            }
        }
}

// ---------------------------------------------------------------------------
// Kernel 3: window attention over one chunk (1024 windows). BARRIER-FREE:
// each wave owns (window, 4 heads) with private vts/ps LDS. q/k fragments
// loaded directly from global qkv in MFMA layout; v via transpose-scatter.
// Softmax / P round-trip / PV identical to the validated rounds.
// ---------------------------------------------------------------------------
__global__ __launch_bounds__(256, 2) void k_attn(
    const bf16*  __restrict__ qkv,   // chunk: (65536, 1536) bf16, rows local
    const float* __restrict__ rpe,   // (16,64,64) f32
    const float* __restrict__ mask,  // (64,64,64) f32
    bf16* __restrict__ ao,           // (2048,64,512) bf16 (global rows)
    int winbase)                     // pass * 1024
{
    __shared__ bf16 vts[4][32 * 72]; // per-wave v^T [32 d][64 tok pad 72]
    __shared__ bf16 ps[4][64 * 72];  // per-wave P   [64 q ][64 tok pad 72]

    const int tid  = threadIdx.x;
    const int lane = tid & 63;
    const int wave = tid >> 6;
    const int lr   = lane & 15;
    const int lg   = lane >> 4;
    const int bw   = blockIdx.x;          // local window 0..1023
    const int gw   = winbase + bw;        // global window
    const int wi   = gw & 63;             // mask index
    const size_t qbase = (size_t)bw * 64 * 1536;
    const float* mp = mask + (size_t)wi * 4096;
    bf16* pvt = &vts[wave][0];
    bf16* pps = &ps[wave][0];

    const float SCALE = 0.17677669529663687f;  // 32^-0.5

    for (int hh = 0; hh < 4; ++hh) {
        const int h  = wave * 4 + hh;
        const int hc = h * 32;
        const float* rp = rpe + (size_t)h * 4096;

        // ---- q/k fragments straight from global (row=*16+lr, k=lg*8) -------
        bf16x8_t qf[4], kf[4];
#pragma unroll
        for (int t = 0; t < 4; ++t) {
            qf[t] = *(const bf16x8_t*)(qkv + qbase + (size_t)(t * 16 + lr) * 1536 + hc + lg * 8);
            kf[t] = *(const bf16x8_t*)(qkv + qbase + (size_t)(t * 16 + lr) * 1536 + 512 + hc + lg * 8);
        }
        // ---- v: coalesced load + transpose scatter into vts ----------------
#pragma unroll
        for (int j = 0; j < 4; ++j) {
            bf16x8_t vr = *(const bf16x8_t*)(qkv + qbase +
                (size_t)(j * 16 + (lane >> 2)) * 1536 + 1024 + hc + (lane & 3) * 8);
#pragma unroll
            for (int i = 0; i < 8; ++i)
                pvt[((lane & 3) * 8 + i) * 72 + j * 16 + (lane >> 2)] = vr[i];
        }

        // ---- per 16-row m-tile: S = qk^T, softmax, unnormalized P -> LDS ---
        float sminv[4][4];               // [mt][r] 1/rowsum
#pragma unroll
        for (int mt = 0; mt < 4; ++mt) {
            f32x4_t s[4];
            f32x4_t zero = {};
#pragma unroll
            for (int nt = 0; nt < 4; ++nt)
                s[nt] = MFMA16(qf[mt], kf[nt], zero);
            float rm[4][4];
#pragma unroll
            for (int nt = 0; nt < 4; ++nt) {
                int col = nt * 16 + lr;
#pragma unroll
                for (int r = 0; r < 4; ++r) {
                    int row = mt * 16 + lg * 4 + r;
                    rm[nt][r] = rp[row * 64 + col] + mp[row * 64 + col];
                }
            }
            float mx[4] = {-1e30f, -1e30f, -1e30f, -1e30f};
#pragma unroll
            for (int nt = 0; nt < 4; ++nt)
#pragma unroll
                for (int r = 0; r < 4; ++r) {
                    float tv = s[nt][r] * SCALE + rm[nt][r];
                    s[nt][r] = tv;
                    mx[r] = fmaxf(mx[r], tv);
                }
#pragma unroll
            for (int r = 0; r < 4; ++r) {
                float m = mx[r];
                m = fmaxf(m, __shfl_xor(m, 1));
                m = fmaxf(m, __shfl_xor(m, 2));
                m = fmaxf(m, __shfl_xor(m, 4));
                m = fmaxf(m, __shfl_xor(m, 8));
                mx[r] = m;
            }
            float sm[4] = {0.f, 0.f, 0.f, 0.f};
#pragma unroll
            for (int nt = 0; nt < 4; ++nt)
#pragma unroll
                for (int r = 0; r < 4; ++r) {
                    float e = __expf(s[nt][r] - mx[r]);
                    s[nt][r] = e;
                    sm[r] += e;
                }
#pragma unroll
            for (int r = 0; r < 4; ++r) {
                float ssum = sm[r];
                ssum += __shfl_xor(ssum, 1);
                ssum += __shfl_xor(ssum, 2);
                ssum += __shfl_xor(ssum, 4);
                ssum += __shfl_xor(ssum, 8);
                sminv[mt][r] = 1.0f / ssum;
            }
#pragma unroll
            for (int nt = 0; nt < 4; ++nt)
#pragma unroll
                for (int r = 0; r < 4; ++r)
                    pps[(mt * 16 + lg * 4 + r) * 72 + nt * 16 + lr] = (bf16)s[nt][r];
        }

        // ---- O = P V per m-tile; normalize at write -------------------------
#pragma unroll
        for (int mt = 0; mt < 4; ++mt) {
            f32x4_t o[2] = {};
#pragma unroll
            for (int ks = 0; ks < 2; ++ks) {
                bf16x8_t pa = *(const bf16x8_t*)&pps[(mt * 16 + lr) * 72 + ks * 32 + lg * 8];
#pragma unroll
                for (int jd = 0; jd < 2; ++jd) {
                    bf16x8_t bv = *(const bf16x8_t*)&pvt[(jd * 16 + lr) * 72 + ks * 32 + lg * 8];
                    o[jd] = MFMA16(pa, bv, o[jd]);
                }
            }
#pragma unroll
            for (int jd = 0; jd < 2; ++jd)
#pragma unroll
                for (int r = 0; r < 4; ++r) {
                    size_t row = (size_t)gw * 64 + mt * 16 + lg * 4 + r;
                    ao[row * 512 + hc + jd * 16 + lr] = (bf16)(o[jd][r] * sminv[mt][r]);
                }
        }
        // next head reuses pvt/pps: same-wave DS ops are in-order -> safe
    }
}

// ---------------------------------------------------------------------------
// Kernel 4: proj GEMM. out[131072,512] = ao@proj_w^T + bias, f32. (unchanged)
// ---------------------------------------------------------------------------
__global__ __launch_bounds__(256) void k_proj(
    const bf16* __restrict__ A, const bf16* __restrict__ Bw,
    const float* __restrict__ bias, float* __restrict__ C)
{
    __shared__ bf16 As[128 * 72];
    __shared__ bf16 Bs[128 * 72];

    const int tid  = threadIdx.x;
    const int lane = tid & 63;
    const int wave = tid >> 6;
    const int lr = lane & 15, lg = lane >> 4;
    const int wr = wave >> 1, wc = wave & 1;
    const int bid = blockIdx.x;                  // 0..4095
    const int wg  = (bid & 7) * 512 + (bid >> 3);
    const int mb = wg >> 2, nb = wg & 3;
    const size_t m0 = (size_t)mb * 128;
    const int n0 = nb * 128;

    f32x4_t acc[4][4] = {};

    for (int kt = 0; kt < 8; ++kt) {
        const int k0 = kt * 64;
        bf16x8_t va[4], vb[4];
#pragma unroll
        for (int j = 0; j < 4; ++j) {
            int c = tid + 256 * j;
            int row = c >> 3, i8 = (c & 7) * 8;
            va[j] = *(const bf16x8_t*)(A  + (m0 + row) * 512 + k0 + i8);
            vb[j] = *(const bf16x8_t*)(Bw + (size_t)(n0 + row) * 512 + k0 + i8);
        }
        __syncthreads();
#pragma unroll
        for (int j = 0; j < 4; ++j) {
            int c = tid + 256 * j;
            int row = c >> 3, i8 = (c & 7) * 8;
            *(bf16x8_t*)&As[row * 72 + i8] = va[j];
            *(bf16x8_t*)&Bs[row * 72 + i8] = vb[j];
        }
        __syncthreads();

#pragma unroll
        for (int k2 = 0; k2 < 2; ++k2) {
            bf16x8_t af[4], bfr[4];
#pragma unroll
            for (int i = 0; i < 4; ++i)
                af[i] = *(const bf16x8_t*)&As[(wr * 64 + i * 16 + lr) * 72 + k2 * 32 + lg * 8];
#pragma unroll
            for (int j = 0; j < 4; ++j)
                bfr[j] = *(const bf16x8_t*)&Bs[(wc * 64 + j * 16 + lr) * 72 + k2 * 32 + lg * 8];
#pragma unroll
            for (int i = 0; i < 4; ++i)
#pragma unroll
                for (int j = 0; j < 4; ++j)
                    acc[i][j] = MFMA16(af[i], bfr[j], acc[i][j]);
        }
    }

    float bj[4];
#pragma unroll
    for (int j = 0; j < 4; ++j) bj[j] = bias[n0 + wc * 64 + j * 16 + lr];
#pragma unroll
    for (int i = 0; i < 4; ++i)
#pragma unroll
        for (int j = 0; j < 4; ++j) {
            int col = n0 + wc * 64 + j * 16 + lr;
#pragma unroll
            for (int r = 0; r < 4; ++r) {
                size_t row = m0 + wr * 64 + i * 16 + lg * 4 + r;
                C[row * 512 + col] = acc[i][j][r] + bj[j];
            }
        }
}

// ---------------------------------------------------------------------------
extern "C" void kernel_launch(void* const* d_in, const int* in_sizes, int n_in,
                              void* d_out, int out_size, void* d_ws, size_t ws_size,
                              hipStream_t stream) {
    (void)in_sizes; (void)n_in; (void)out_size; (void)ws_size;
    const float* x      = (const float*)d_in[0];
    const float* pe     = (const float*)d_in[1];
    const float* rpe    = (const float*)d_in[2];
    const float* mask   = (const float*)d_in[3];
    const float* qkv_b  = (const float*)d_in[5];
    const float* qkv_w  = (const float*)d_in[4];
    const float* proj_w = (const float*)d_in[6];
    const float* proj_b = (const float*)d_in[7];
    float* out = (float*)d_out;

    char* ws = (char*)d_ws;
    bf16* wqkvb  = (bf16*)ws;                    // 1,572,864 B
    bf16* wprojb = (bf16*)(ws + 1572864);        //   524,288 B
    bf16* ao     = (bf16*)(ws + 2097152);        // 134,217,728 B (total 136.3 MB)
    bf16* qkvscr = (bf16*)d_out;                 // 201 MB chunk scratch in d_out
                                                 // (dead before k_proj writes out)

    k_wprep<<<256, 256, 0, stream>>>(qkv_w, proj_w, wqkvb, wprojb);
    for (int pass = 0; pass < 2; ++pass) {
        k_qkv<<<6144, 256, 0, stream>>>(x + (size_t)pass * 65536 * 512, pe,
                                        wqkvb, qkv_b, qkvscr);
        k_attn<<<1024, 256, 0, stream>>>(qkvscr, rpe, mask, ao, pass * 1024);
    }
    k_proj<<<4096, 256, 0, stream>>>(ao, wprojb, proj_b, out);
}

// Round 6
// 839.905 us; speedup vs baseline: 1.1839x; 1.1839x over previous
//
#include <hip/hip_runtime.h>
#include <hip/hip_bf16.h>
#include <cstdint>

// Problem: B_=2048 windows, N=64 tokens, C=512, H=16 heads, hd=32, nW=64.
// Pipeline: k_wprep -> 2x { k_qkv (dbuf GEMM, x+pe fused, d_out as scratch)
//                            -> k_attn (barrier-free) } -> k_proj (dbuf GEMM).
typedef __bf16 bf16;
typedef __bf16 bf16x8_t __attribute__((ext_vector_type(8)));
typedef __bf16 bf16x4_t __attribute__((ext_vector_type(4)));
typedef float  f32x4_t  __attribute__((ext_vector_type(4)));

#define MFMA16(a, b, c) __builtin_amdgcn_mfma_f32_16x16x32_bf16((a), (b), (c), 0, 0, 0)

// ---------------------------------------------------------------------------
// Kernel 1: convert weights to bf16 (qkv_w 1536x512, proj_w 512x512)
// ---------------------------------------------------------------------------
__global__ void k_wprep(const float* __restrict__ wq, const float* __restrict__ wp,
                        bf16* __restrict__ wqb, bf16* __restrict__ wpb) {
    int t = blockIdx.x * 256 + threadIdx.x;
    int stride = gridDim.x * 256;
    for (int i = t; i < 196608; i += stride) {
        float4 v = ((const float4*)wq)[i];
        bf16x4_t o; o[0]=(bf16)v.x; o[1]=(bf16)v.y; o[2]=(bf16)v.z; o[3]=(bf16)v.w;
        ((bf16x4_t*)wqb)[i] = o;
    }
    for (int i = t; i < 65536; i += stride) {
        float4 v = ((const float4*)wp)[i];
        bf16x4_t o; o[0]=(bf16)v.x; o[1]=(bf16)v.y; o[2]=(bf16)v.z; o[3]=(bf16)v.w;
        ((bf16x4_t*)wpb)[i] = o;
    }
}

// ---------------------------------------------------------------------------
// Kernel 2: QKV GEMM over one M-chunk (65536 rows), double-buffered.
// C[65536,1536] = bf16( (x+pe)[m,:] @ qkv_w^T + qkv_b ).  128x128 tile, BK=64,
// 4 waves. Loop: issue loads(kt+1) -> compute buf[kt&1] -> ds_write other buf
// -> ONE barrier. Load latency hides under compute.
// ---------------------------------------------------------------------------
__global__ __launch_bounds__(256, 2) void k_qkv(
    const float* __restrict__ x,     // chunk base: (65536, 512) f32
    const float* __restrict__ pe,    // (64, 512) f32
    const bf16*  __restrict__ Bw,    // (1536, 512) bf16
    const float* __restrict__ bias,  // (1536,) f32
    bf16* __restrict__ Cq)           // chunk out: (65536, 1536) bf16
{
    __shared__ bf16 As[2][128 * 72];
    __shared__ bf16 Bs[2][128 * 72];

    const int tid  = threadIdx.x;
    const int lane = tid & 63;
    const int wave = tid >> 6;
    const int lr = lane & 15, lg = lane >> 4;
    const int wr = wave >> 1, wc = wave & 1;
    const int bid = blockIdx.x;                   // 0..6143 (= 8 * 768)
    const int wg  = (bid & 7) * 768 + (bid >> 3); // XCD-contiguous chunks
    const int mb  = wg / 12, nb = wg - mb * 12;   // 512 x 12
    const size_t m0 = (size_t)mb * 128;
    const int n0 = nb * 128;

    const int row = tid >> 3;              // staging row stride-32 pattern
    const int i8  = (tid & 7) * 8;

    f32x4_t acc[4][4] = {};
    bf16x8_t va[4], vb[4];

    // ---- staging helpers (each j covers rows row+32*j) -----------------------
    auto load_ab = [&](int kt) {
        const int k0 = kt * 64;
#pragma unroll
        for (int j = 0; j < 4; ++j) {
            int r = row + 32 * j;
            const float* xr = x  + (m0 + r) * 512 + k0 + i8;
            const float* pr = pe + (size_t)(r & 63) * 512 + k0 + i8;   // m0%64==0
            float4 x0 = *(const float4*)(xr);
            float4 x1 = *(const float4*)(xr + 4);
            float4 p0 = *(const float4*)(pr);
            float4 p1 = *(const float4*)(pr + 4);
            bf16x8_t v;
            v[0]=(bf16)(x0.x+p0.x); v[1]=(bf16)(x0.y+p0.y);
            v[2]=(bf16)(x0.z+p0.z); v[3]=(bf16)(x0.w+p0.w);
            v[4]=(bf16)(x1.x+p1.x); v[5]=(bf16)(x1.y+p1.y);
            v[6]=(bf16)(x1.z+p1.z); v[7]=(bf16)(x1.w+p1.w);
            va[j] = v;
            vb[j] = *(const bf16x8_t*)(Bw + (size_t)(n0 + r) * 512 + k0 + i8);
        }
    };
    auto write_lds = [&](int buf) {
#pragma unroll
        for (int j = 0; j < 4; ++j) {
            int r = row + 32 * j;
            *(bf16x8_t*)&As[buf][r * 72 + i8] = va[j];
            *(bf16x8_t*)&Bs[buf][r * 72 + i8] = vb[j];
        }
    };

    // ---- prologue: kt=0 into buf 0 ------------------------------------------
    load_ab(0);
    write_lds(0);
    __syncthreads();

    for (int kt = 0; kt < 8; ++kt) {
        if (kt < 7) load_ab(kt + 1);       // issue next tile's loads early
        const int cur = kt & 1;
#pragma unroll
        for (int k2 = 0; k2 < 2; ++k2) {
            bf16x8_t af[4], bfr[4];
#pragma unroll
            for (int i = 0; i < 4; ++i)
                af[i] = *(const bf16x8_t*)&As[cur][(wr * 64 + i * 16 + lr) * 72 + k2 * 32 + lg * 8];
#pragma unroll
            for (int j = 0; j < 4; ++j)
                bfr[j] = *(const bf16x8_t*)&Bs[cur][(wc * 64 + j * 16 + lr) * 72 + k2 * 32 + lg * 8];
#pragma unroll
            for (int i = 0; i < 4; ++i)
#pragma unroll
                for (int j = 0; j < 4; ++j)
                    acc[i][j] = MFMA16(af[i], bfr[j], acc[i][j]);
        }
        if (kt < 7) {
            write_lds(cur ^ 1);            // vmcnt drain hidden under compute;
            __syncthreads();               // other buf last read 2 barriers ago
        }
    }

    float bj[4];
#pragma unroll
    for (int j = 0; j < 4; ++j) bj[j] = bias[n0 + wc * 64 + j * 16 + lr];
#pragma unroll
    for (int i = 0; i < 4; ++i)
#pragma unroll
        for (int j = 0; j < 4; ++j) {
            int col = n0 + wc * 64 + j * 16 + lr;
#pragma unroll
            for (int r = 0; r < 4; ++r) {
                size_t rw = m0 + wr * 64 + i * 16 + lg * 4 + r;
                Cq[rw * 1536 + col] = (bf16)(acc[i][j][r] + bj[j]);
            }
        }
}

// ---------------------------------------------------------------------------
// Kernel 3: window attention over one chunk (1024 windows). BARRIER-FREE:
// each wave owns (window, 4 heads) with private vts/ps LDS. (unchanged R5)
// ---------------------------------------------------------------------------
__global__ __launch_bounds__(256, 2) void k_attn(
    const bf16*  __restrict__ qkv,   // chunk: (65536, 1536) bf16, rows local
    const float* __restrict__ rpe,   // (16,64,64) f32
    const float* __restrict__ mask,  // (64,64,64) f32
    bf16* __restrict__ ao,           // (2048,64,512) bf16 (global rows)
    int winbase)                     // pass * 1024
{
    __shared__ bf16 vts[4][32 * 72]; // per-wave v^T [32 d][64 tok pad 72]
    __shared__ bf16 ps[4][64 * 72];  // per-wave P   [64 q ][64 tok pad 72]

    const int tid  = threadIdx.x;
    const int lane = tid & 63;
    const int wave = tid >> 6;
    const int lr   = lane & 15;
    const int lg   = lane >> 4;
    const int bw   = blockIdx.x;          // local window 0..1023
    const int gw   = winbase + bw;        // global window
    const int wi   = gw & 63;             // mask index
    const size_t qbase = (size_t)bw * 64 * 1536;
    const float* mp = mask + (size_t)wi * 4096;
    bf16* pvt = &vts[wave][0];
    bf16* pps = &ps[wave][0];

    const float SCALE = 0.17677669529663687f;  // 32^-0.5

    for (int hh = 0; hh < 4; ++hh) {
        const int h  = wave * 4 + hh;
        const int hc = h * 32;
        const float* rp = rpe + (size_t)h * 4096;

        // ---- q/k fragments straight from global (row=*16+lr, k=lg*8) -------
        bf16x8_t qf[4], kf[4];
#pragma unroll
        for (int t = 0; t < 4; ++t) {
            qf[t] = *(const bf16x8_t*)(qkv + qbase + (size_t)(t * 16 + lr) * 1536 + hc + lg * 8);
            kf[t] = *(const bf16x8_t*)(qkv + qbase + (size_t)(t * 16 + lr) * 1536 + 512 + hc + lg * 8);
        }
        // ---- v: coalesced load + transpose scatter into vts ----------------
#pragma unroll
        for (int j = 0; j < 4; ++j) {
            bf16x8_t vr = *(const bf16x8_t*)(qkv + qbase +
                (size_t)(j * 16 + (lane >> 2)) * 1536 + 1024 + hc + (lane & 3) * 8);
#pragma unroll
            for (int i = 0; i < 8; ++i)
                pvt[((lane & 3) * 8 + i) * 72 + j * 16 + (lane >> 2)] = vr[i];
        }

        // ---- per 16-row m-tile: S = qk^T, softmax, unnormalized P -> LDS ---
        float sminv[4][4];               // [mt][r] 1/rowsum
#pragma unroll
        for (int mt = 0; mt < 4; ++mt) {
            f32x4_t s[4];
            f32x4_t zero = {};
#pragma unroll
            for (int nt = 0; nt < 4; ++nt)
                s[nt] = MFMA16(qf[mt], kf[nt], zero);
            float rm[4][4];
#pragma unroll
            for (int nt = 0; nt < 4; ++nt) {
                int col = nt * 16 + lr;
#pragma unroll
                for (int r = 0; r < 4; ++r) {
                    int rrow = mt * 16 + lg * 4 + r;
                    rm[nt][r] = rp[rrow * 64 + col] + mp[rrow * 64 + col];
                }
            }
            float mx[4] = {-1e30f, -1e30f, -1e30f, -1e30f};
#pragma unroll
            for (int nt = 0; nt < 4; ++nt)
#pragma unroll
                for (int r = 0; r < 4; ++r) {
                    float tv = s[nt][r] * SCALE + rm[nt][r];
                    s[nt][r] = tv;
                    mx[r] = fmaxf(mx[r], tv);
                }
#pragma unroll
            for (int r = 0; r < 4; ++r) {
                float m = mx[r];
                m = fmaxf(m, __shfl_xor(m, 1));
                m = fmaxf(m, __shfl_xor(m, 2));
                m = fmaxf(m, __shfl_xor(m, 4));
                m = fmaxf(m, __shfl_xor(m, 8));
                mx[r] = m;
            }
            float sm[4] = {0.f, 0.f, 0.f, 0.f};
#pragma unroll
            for (int nt = 0; nt < 4; ++nt)
#pragma unroll
                for (int r = 0; r < 4; ++r) {
                    float e = __expf(s[nt][r] - mx[r]);
                    s[nt][r] = e;
                    sm[r] += e;
                }
#pragma unroll
            for (int r = 0; r < 4; ++r) {
                float ssum = sm[r];
                ssum += __shfl_xor(ssum, 1);
                ssum += __shfl_xor(ssum, 2);
                ssum += __shfl_xor(ssum, 4);
                ssum += __shfl_xor(ssum, 8);
                sminv[mt][r] = 1.0f / ssum;
            }
#pragma unroll
            for (int nt = 0; nt < 4; ++nt)
#pragma unroll
                for (int r = 0; r < 4; ++r)
                    pps[(mt * 16 + lg * 4 + r) * 72 + nt * 16 + lr] = (bf16)s[nt][r];
        }

        // ---- O = P V per m-tile; normalize at write -------------------------
#pragma unroll
        for (int mt = 0; mt < 4; ++mt) {
            f32x4_t o[2] = {};
#pragma unroll
            for (int ks = 0; ks < 2; ++ks) {
                bf16x8_t pa = *(const bf16x8_t*)&pps[(mt * 16 + lr) * 72 + ks * 32 + lg * 8];
#pragma unroll
                for (int jd = 0; jd < 2; ++jd) {
                    bf16x8_t bv = *(const bf16x8_t*)&pvt[(jd * 16 + lr) * 72 + ks * 32 + lg * 8];
                    o[jd] = MFMA16(pa, bv, o[jd]);
                }
            }
#pragma unroll
            for (int jd = 0; jd < 2; ++jd)
#pragma unroll
                for (int r = 0; r < 4; ++r) {
                    size_t rrow = (size_t)gw * 64 + mt * 16 + lg * 4 + r;
                    ao[rrow * 512 + hc + jd * 16 + lr] = (bf16)(o[jd][r] * sminv[mt][r]);
                }
        }
        // next head reuses pvt/pps: same-wave DS ops are in-order -> safe
    }
}

// ---------------------------------------------------------------------------
// Kernel 4: proj GEMM, double-buffered (same loop as k_qkv).
// out[131072,512] = ao@proj_w^T + bias, f32.
// ---------------------------------------------------------------------------
__global__ __launch_bounds__(256, 2) void k_proj(
    const bf16* __restrict__ A, const bf16* __restrict__ Bw,
    const float* __restrict__ bias, float* __restrict__ C)
{
    __shared__ bf16 As[2][128 * 72];
    __shared__ bf16 Bs[2][128 * 72];

    const int tid  = threadIdx.x;
    const int lane = tid & 63;
    const int wave = tid >> 6;
    const int lr = lane & 15, lg = lane >> 4;
    const int wr = wave >> 1, wc = wave & 1;
    const int bid = blockIdx.x;                  // 0..4095
    const int wg  = (bid & 7) * 512 + (bid >> 3);
    const int mb = wg >> 2, nb = wg & 3;
    const size_t m0 = (size_t)mb * 128;
    const int n0 = nb * 128;

    const int row = tid >> 3;
    const int i8  = (tid & 7) * 8;

    f32x4_t acc[4][4] = {};
    bf16x8_t va[4], vb[4];

    auto load_ab = [&](int kt) {
        const int k0 = kt * 64;
#pragma unroll
        for (int j = 0; j < 4; ++j) {
            int r = row + 32 * j;
            va[j] = *(const bf16x8_t*)(A  + (m0 + r) * 512 + k0 + i8);
            vb[j] = *(const bf16x8_t*)(Bw + (size_t)(n0 + r) * 512 + k0 + i8);
        }
    };
    auto write_lds = [&](int buf) {
#pragma unroll
        for (int j = 0; j < 4; ++j) {
            int r = row + 32 * j;
            *(bf16x8_t*)&As[buf][r * 72 + i8] = va[j];
            *(bf16x8_t*)&Bs[buf][r * 72 + i8] = vb[j];
        }
    };

    load_ab(0);
    write_lds(0);
    __syncthreads();

    for (int kt = 0; kt < 8; ++kt) {
        if (kt < 7) load_ab(kt + 1);
        const int cur = kt & 1;
#pragma unroll
        for (int k2 = 0; k2 < 2; ++k2) {
            bf16x8_t af[4], bfr[4];
#pragma unroll
            for (int i = 0; i < 4; ++i)
                af[i] = *(const bf16x8_t*)&As[cur][(wr * 64 + i * 16 + lr) * 72 + k2 * 32 + lg * 8];
#pragma unroll
            for (int j = 0; j < 4; ++j)
                bfr[j] = *(const bf16x8_t*)&Bs[cur][(wc * 64 + j * 16 + lr) * 72 + k2 * 32 + lg * 8];
#pragma unroll
            for (int i = 0; i < 4; ++i)
#pragma unroll
                for (int j = 0; j < 4; ++j)
                    acc[i][j] = MFMA16(af[i], bfr[j], acc[i][j]);
        }
        if (kt < 7) {
            write_lds(cur ^ 1);
            __syncthreads();
        }
    }

    float bj[4];
#pragma unroll
    for (int j = 0; j < 4; ++j) bj[j] = bias[n0 + wc * 64 + j * 16 + lr];
#pragma unroll
    for (int i = 0; i < 4; ++i)
#pragma unroll
        for (int j = 0; j < 4; ++j) {
            int col = n0 + wc * 64 + j * 16 + lr;
#pragma unroll
            for (int r = 0; r < 4; ++r) {
                size_t rw = m0 + wr * 64 + i * 16 + lg * 4 + r;
                C[rw * 512 + col] = acc[i][j][r] + bj[j];
            }
        }
}

// ---------------------------------------------------------------------------
extern "C" void kernel_launch(void* const* d_in, const int* in_sizes, int n_in,
                              void* d_out, int out_size, void* d_ws, size_t ws_size,
                              hipStream_t stream) {
    (void)in_sizes; (void)n_in; (void)out_size; (void)ws_size;
    const float* x      = (const float*)d_in[0];
    const float* pe     = (const float*)d_in[1];
    const float* rpe    = (const float*)d_in[2];
    const float* mask   = (const float*)d_in[3];
    const float* qkv_w  = (const float*)d_in[4];
    const float* qkv_b  = (const float*)d_in[5];
    const float* proj_w = (const float*)d_in[6];
    const float* proj_b = (const float*)d_in[7];
    float* out = (float*)d_out;

    char* ws = (char*)d_ws;
    bf16* wqkvb  = (bf16*)ws;                    // 1,572,864 B
    bf16* wprojb = (bf16*)(ws + 1572864);        //   524,288 B
    bf16* ao     = (bf16*)(ws + 2097152);        // 134,217,728 B (total 136.3 MB)
    bf16* qkvscr = (bf16*)d_out;                 // 201 MB chunk scratch in d_out
                                                 // (dead before k_proj writes out)

    k_wprep<<<256, 256, 0, stream>>>(qkv_w, proj_w, wqkvb, wprojb);
    for (int pass = 0; pass < 2; ++pass) {
        k_qkv<<<6144, 256, 0, stream>>>(x + (size_t)pass * 65536 * 512, pe,
                                        wqkvb, qkv_b, qkvscr);
        k_attn<<<1024, 256, 0, stream>>>(qkvscr, rpe, mask, ao, pass * 1024);
    }
    k_proj<<<4096, 256, 0, stream>>>(ao, wprojb, proj_b, out);
}

// Round 8
// 784.868 us; speedup vs baseline: 1.2669x; 1.0701x over previous
//
#include <hip/hip_runtime.h>
#include <hip/hip_bf16.h>
#include <cstdint>

// Problem: B_=2048 windows, N=64 tokens, C=512, H=16 heads, hd=32, nW=64.
// Pipeline: k_wprep, k_xprep(xp=bf16(x+pe), d_out[0..128M)) ->
//   4x { k_qkv (pure-gload_lds 2-phase GEMM, head-major chunk out)
//        -> k_attn (barrier-free) } -> k_proj.
typedef __bf16 bf16;
typedef __bf16 bf16x8_t __attribute__((ext_vector_type(8)));
typedef __bf16 bf16x4_t __attribute__((ext_vector_type(4)));
typedef float  f32x4_t  __attribute__((ext_vector_type(4)));

#define MFMA16(a, b, c) __builtin_amdgcn_mfma_f32_16x16x32_bf16((a), (b), (c), 0, 0, 0)

__device__ __forceinline__ void gload_lds16(const bf16* g, bf16* l) {
    __builtin_amdgcn_global_load_lds(
        (const __attribute__((address_space(1))) void*)g,
        (__attribute__((address_space(3))) void*)l,
        16, 0, 0);
}

// ---------------------------------------------------------------------------
// Kernel 1: convert weights to bf16 (qkv_w 1536x512, proj_w 512x512)
// ---------------------------------------------------------------------------
__global__ void k_wprep(const float* __restrict__ wq, const float* __restrict__ wp,
                        bf16* __restrict__ wqb, bf16* __restrict__ wpb) {
    int t = blockIdx.x * 256 + threadIdx.x;
    int stride = gridDim.x * 256;
    for (int i = t; i < 196608; i += stride) {
        float4 v = ((const float4*)wq)[i];
        bf16x4_t o; o[0]=(bf16)v.x; o[1]=(bf16)v.y; o[2]=(bf16)v.z; o[3]=(bf16)v.w;
        ((bf16x4_t*)wqb)[i] = o;
    }
    for (int i = t; i < 65536; i += stride) {
        float4 v = ((const float4*)wp)[i];
        bf16x4_t o; o[0]=(bf16)v.x; o[1]=(bf16)v.y; o[2]=(bf16)v.z; o[3]=(bf16)v.w;
        ((bf16x4_t*)wpb)[i] = o;
    }
}

// ---------------------------------------------------------------------------
// Kernel 2: xp[131072][512] = bf16(x + pe)  (one shot, memory-bound)
// ---------------------------------------------------------------------------
__global__ void k_xprep(const float* __restrict__ x, const float* __restrict__ pe,
                        bf16* __restrict__ xp) {
    int t = blockIdx.x * 256 + threadIdx.x;
    int stride = gridDim.x * 256;
    for (int i = t; i < 8388608; i += stride) {     // 131072*512/8 groups of 8
        int row = i >> 6;
        int g   = (i & 63) * 8;
        const float* xr = x  + ((size_t)row << 9) + g;
        const float* pr = pe + ((size_t)(row & 63) << 9) + g;
        float4 x0 = *(const float4*)(xr);
        float4 x1 = *(const float4*)(xr + 4);
        float4 p0 = *(const float4*)(pr);
        float4 p1 = *(const float4*)(pr + 4);
        bf16x8_t v;
        v[0]=(bf16)(x0.x+p0.x); v[1]=(bf16)(x0.y+p0.y);
        v[2]=(bf16)(x0.z+p0.z); v[3]=(bf16)(x0.w+p0.w);
        v[4]=(bf16)(x1.x+p1.x); v[5]=(bf16)(x1.y+p1.y);
        v[6]=(bf16)(x1.z+p1.z); v[7]=(bf16)(x1.w+p1.w);
        *(bf16x8_t*)(xp + (size_t)i * 8) = v;
    }
}

// ---------------------------------------------------------------------------
// Kernel 3: QKV GEMM over one 32768-row chunk. 128x128 tile, BK=64.
// PURE gload_lds staging (8/wave/iter, both operands XOR-swizzled), exact
// counted vmcnt(8), raw barriers + sched_barrier fences. r3-proven skeleton;
// no raw registers live across compute -> no spill -> vmcnt counts exact.
// Output head-major per chunk: [3][16][512 win][64 tok][32 d] bf16.
// ---------------------------------------------------------------------------
__global__ __launch_bounds__(256, 2) void k_qkv(
    const bf16*  __restrict__ A,     // chunk xp: (32768, 512) bf16
    const bf16*  __restrict__ Bw,    // (1536, 512) bf16
    const float* __restrict__ bias,  // (1536,) f32
    bf16* __restrict__ Cq)           // chunk out, head-major (100.7 MB)
{
    __shared__ bf16 As[2][128 * 64]; // linear, XOR-swizzled pieces
    __shared__ bf16 Bs[2][128 * 64];
    // LDS 65,536 B -> 2 blocks/CU

    const int tid  = threadIdx.x;
    const int lane = tid & 63;
    const int wave = tid >> 6;
    const int lr = lane & 15, lg = lane >> 4;
    const int wr = wave >> 1, wc = wave & 1;
    const int bid = blockIdx.x;                   // 0..3071 (= 8 * 384)
    const int wg  = (bid & 7) * 384 + (bid >> 3); // XCD-contiguous chunks
    const int mb  = wg / 12, nb = wg - mb * 12;   // 256 x 12
    const size_t m0 = (size_t)mb * 128;
    const int n0 = nb * 128;

    f32x4_t acc[4][4] = {};

    auto stage = [&](int kt, int buf) {
        const int k0 = kt * 64;
#pragma unroll
        for (int ii = 0; ii < 4; ++ii) {
            int instr = wave * 4 + ii;           // 0..15, 1KB each
            int r  = instr * 8 + (lane >> 3);    // tile row 0..127
            int gp = (lane & 7) ^ (r & 7);       // pre-swizzled source piece
            gload_lds16(A  + (m0 + r) * 512 + k0 + gp * 8, &As[buf][instr * 512]);
            gload_lds16(Bw + (size_t)(n0 + r) * 512 + k0 + gp * 8, &Bs[buf][instr * 512]);
        }
    };

    stage(0, 0);

    for (int kt = 0; kt < 8; ++kt) {
        const int cur = kt & 1;
        if (kt < 7) {
            stage(kt + 1, cur ^ 1);
            asm volatile("s_waitcnt vmcnt(8) lgkmcnt(0)" ::: "memory");
        } else {
            asm volatile("s_waitcnt vmcnt(0) lgkmcnt(0)" ::: "memory");
        }
        __builtin_amdgcn_sched_barrier(0);
        __builtin_amdgcn_s_barrier();            // buf[cur] staged, all waves
        __builtin_amdgcn_sched_barrier(0);

#pragma unroll
        for (int k2 = 0; k2 < 2; ++k2) {
            bf16x8_t af[4], bfr[4];
#pragma unroll
            for (int i = 0; i < 4; ++i) {
                int rowa = wr * 64 + i * 16 + lr;
                int ph   = (k2 * 4 + lg) ^ (rowa & 7);
                af[i] = *(const bf16x8_t*)&As[cur][rowa * 64 + ph * 8];
            }
#pragma unroll
            for (int j = 0; j < 4; ++j) {
                int rowb = wc * 64 + j * 16 + lr;
                int ph   = (k2 * 4 + lg) ^ (rowb & 7);
                bfr[j] = *(const bf16x8_t*)&Bs[cur][rowb * 64 + ph * 8];
            }
#pragma unroll
            for (int i = 0; i < 4; ++i)
#pragma unroll
                for (int j = 0; j < 4; ++j)
                    acc[i][j] = MFMA16(af[i], bfr[j], acc[i][j]);
        }

        if (kt < 7) {
            asm volatile("s_waitcnt lgkmcnt(0)" ::: "memory");  // my reads retired
            __builtin_amdgcn_sched_barrier(0);
            __builtin_amdgcn_s_barrier();        // all reads done -> overwrite ok
            __builtin_amdgcn_sched_barrier(0);
        }
    }

    // ---- epilogue: bias + head-major store ----------------------------------
    float bj[4];
#pragma unroll
    for (int j = 0; j < 4; ++j) bj[j] = bias[n0 + wc * 64 + j * 16 + lr];
#pragma unroll
    for (int i = 0; i < 4; ++i)
#pragma unroll
        for (int j = 0; j < 4; ++j) {
            int col   = n0 + wc * 64 + j * 16 + lr;    // 0..1535
            int which = col >> 9;
            int h     = (col >> 5) & 15;
            int d     = col & 31;
            bf16* base = Cq + (size_t)(which * 16 + h) * (512 * 2048);
#pragma unroll
            for (int r = 0; r < 4; ++r) {
                int mrow = (int)m0 + wr * 64 + i * 16 + lg * 4 + r;
                int win = mrow >> 6, tok = mrow & 63;  // win 0..511 local
                base[(size_t)win * 2048 + tok * 32 + d] = (bf16)(acc[i][j][r] + bj[j]);
            }
        }
}

// ---------------------------------------------------------------------------
// Kernel 4: window attention over one 512-window chunk. BARRIER-FREE:
// each wave owns (window, 4 heads), private vts/ps LDS. Head-major input.
// ---------------------------------------------------------------------------
__global__ __launch_bounds__(256, 2) void k_attn(
    const bf16*  __restrict__ qkv,   // chunk head-major [3][16][512][64][32]
    const float* __restrict__ rpe,   // (16,64,64) f32
    const float* __restrict__ mask,  // (64,64,64) f32
    bf16* __restrict__ ao,           // (2048,64,512) bf16 (global rows)
    int winbase)                     // chunk * 512
{
    __shared__ bf16 vts[4][32 * 72]; // per-wave v^T [32 d][64 tok pad 72]
    __shared__ bf16 ps[4][64 * 72];  // per-wave P   [64 q ][64 tok pad 72]

    const int tid  = threadIdx.x;
    const int lane = tid & 63;
    const int wave = tid >> 6;
    const int lr   = lane & 15;
    const int lg   = lane >> 4;
    const int bw   = blockIdx.x;          // local window 0..511
    const int gw   = winbase + bw;        // global window
    const int wi   = gw & 63;             // mask index
    const float* mp = mask + (size_t)wi * 4096;
    bf16* pvt = &vts[wave][0];
    bf16* pps = &ps[wave][0];

    const float SCALE = 0.17677669529663687f;  // 32^-0.5

    for (int hh = 0; hh < 4; ++hh) {
        const int h  = wave * 4 + hh;
        const float* rp = rpe + (size_t)h * 4096;
        const bf16* qb = qkv + ((size_t)(h)      * 512 + bw) * 2048;
        const bf16* kb = qkv + ((size_t)(16 + h) * 512 + bw) * 2048;
        const bf16* vb = qkv + ((size_t)(32 + h) * 512 + bw) * 2048;

        // ---- q/k fragments: contiguous per tile (tok*32 + d) ---------------
        bf16x8_t qf[4], kf[4];
#pragma unroll
        for (int t = 0; t < 4; ++t) {
            qf[t] = *(const bf16x8_t*)(qb + (t * 16 + lr) * 32 + lg * 8);
            kf[t] = *(const bf16x8_t*)(kb + (t * 16 + lr) * 32 + lg * 8);
        }
        // ---- v: coalesced load + transpose scatter into vts ----------------
#pragma unroll
        for (int j = 0; j < 4; ++j) {
            bf16x8_t vr = *(const bf16x8_t*)(vb + (j * 16 + (lane >> 2)) * 32 + (lane & 3) * 8);
#pragma unroll
            for (int i = 0; i < 8; ++i)
                pvt[((lane & 3) * 8 + i) * 72 + j * 16 + (lane >> 2)] = vr[i];
        }

        // ---- per 16-row m-tile: S = qk^T, softmax, unnormalized P -> LDS ---
        float sminv[4][4];               // [mt][r] 1/rowsum
#pragma unroll
        for (int mt = 0; mt < 4; ++mt) {
            f32x4_t s[4];
            f32x4_t zero = {};
#pragma unroll
            for (int nt = 0; nt < 4; ++nt)
                s[nt] = MFMA16(qf[mt], kf[nt], zero);
            float rm[4][4];
#pragma unroll
            for (int nt = 0; nt < 4; ++nt) {
                int col = nt * 16 + lr;
#pragma unroll
                for (int r = 0; r < 4; ++r) {
                    int rrow = mt * 16 + lg * 4 + r;
                    rm[nt][r] = rp[rrow * 64 + col] + mp[rrow * 64 + col];
                }
            }
            float mx[4] = {-1e30f, -1e30f, -1e30f, -1e30f};
#pragma unroll
            for (int nt = 0; nt < 4; ++nt)
#pragma unroll
                for (int r = 0; r < 4; ++r) {
                    float tv = s[nt][r] * SCALE + rm[nt][r];
                    s[nt][r] = tv;
                    mx[r] = fmaxf(mx[r], tv);
                }
#pragma unroll
            for (int r = 0; r < 4; ++r) {
                float m = mx[r];
                m = fmaxf(m, __shfl_xor(m, 1));
                m = fmaxf(m, __shfl_xor(m, 2));
                m = fmaxf(m, __shfl_xor(m, 4));
                m = fmaxf(m, __shfl_xor(m, 8));
                mx[r] = m;
            }
            float sm[4] = {0.f, 0.f, 0.f, 0.f};
#pragma unroll
            for (int nt = 0; nt < 4; ++nt)
#pragma unroll
                for (int r = 0; r < 4; ++r) {
                    float e = __expf(s[nt][r] - mx[r]);
                    s[nt][r] = e;
                    sm[r] += e;
                }
#pragma unroll
            for (int r = 0; r < 4; ++r) {
                float ssum = sm[r];
                ssum += __shfl_xor(ssum, 1);
                ssum += __shfl_xor(ssum, 2);
                ssum += __shfl_xor(ssum, 4);
                ssum += __shfl_xor(ssum, 8);
                sminv[mt][r] = 1.0f / ssum;
            }
#pragma unroll
            for (int nt = 0; nt < 4; ++nt)
#pragma unroll
                for (int r = 0; r < 4; ++r)
                    pps[(mt * 16 + lg * 4 + r) * 72 + nt * 16 + lr] = (bf16)s[nt][r];
        }

        // ---- O = P V per m-tile; normalize at write -------------------------
#pragma unroll
        for (int mt = 0; mt < 4; ++mt) {
            f32x4_t o[2] = {};
#pragma unroll
            for (int ks = 0; ks < 2; ++ks) {
                bf16x8_t pa = *(const bf16x8_t*)&pps[(mt * 16 + lr) * 72 + ks * 32 + lg * 8];
#pragma unroll
                for (int jd = 0; jd < 2; ++jd) {
                    bf16x8_t bv = *(const bf16x8_t*)&pvt[(jd * 16 + lr) * 72 + ks * 32 + lg * 8];
                    o[jd] = MFMA16(pa, bv, o[jd]);
                }
            }
#pragma unroll
            for (int jd = 0; jd < 2; ++jd)
#pragma unroll
                for (int r = 0; r < 4; ++r) {
                    size_t rrow = (size_t)gw * 64 + mt * 16 + lg * 4 + r;
                    ao[rrow * 512 + h * 32 + jd * 16 + lr] = (bf16)(o[jd][r] * sminv[mt][r]);
                }
        }
        // next head reuses pvt/pps: same-wave DS ops are in-order -> safe
    }
}

// ---------------------------------------------------------------------------
// Kernel 5: proj GEMM, same pure-gload_lds skeleton as k_qkv.
// out[131072,512] = ao@proj_w^T + bias, f32.
// ---------------------------------------------------------------------------
__global__ __launch_bounds__(256, 2) void k_proj(
    const bf16* __restrict__ A, const bf16* __restrict__ Bw,
    const float* __restrict__ bias, float* __restrict__ C)
{
    __shared__ bf16 As[2][128 * 64];
    __shared__ bf16 Bs[2][128 * 64];

    const int tid  = threadIdx.x;
    const int lane = tid & 63;
    const int wave = tid >> 6;
    const int lr = lane & 15, lg = lane >> 4;
    const int wr = wave >> 1, wc = wave & 1;
    const int bid = blockIdx.x;                  // 0..4095
    const int wg  = (bid & 7) * 512 + (bid >> 3);
    const int mb = wg >> 2, nb = wg & 3;
    const size_t m0 = (size_t)mb * 128;
    const int n0 = nb * 128;

    f32x4_t acc[4][4] = {};

    auto stage = [&](int kt, int buf) {
        const int k0 = kt * 64;
#pragma unroll
        for (int ii = 0; ii < 4; ++ii) {
            int instr = wave * 4 + ii;
            int r  = instr * 8 + (lane >> 3);
            int gp = (lane & 7) ^ (r & 7);
            gload_lds16(A  + (m0 + r) * 512 + k0 + gp * 8, &As[buf][instr * 512]);
            gload_lds16(Bw + (size_t)(n0 + r) * 512 + k0 + gp * 8, &Bs[buf][instr * 512]);
        }
    };

    stage(0, 0);

    for (int kt = 0; kt < 8; ++kt) {
        const int cur = kt & 1;
        if (kt < 7) {
            stage(kt + 1, cur ^ 1);
            asm volatile("s_waitcnt vmcnt(8) lgkmcnt(0)" ::: "memory");
        } else {
            asm volatile("s_waitcnt vmcnt(0) lgkmcnt(0)" ::: "memory");
        }
        __builtin_amdgcn_sched_barrier(0);
        __builtin_amdgcn_s_barrier();
        __builtin_amdgcn_sched_barrier(0);

#pragma unroll
        for (int k2 = 0; k2 < 2; ++k2) {
            bf16x8_t af[4], bfr[4];
#pragma unroll
            for (int i = 0; i < 4; ++i) {
                int rowa = wr * 64 + i * 16 + lr;
                int ph   = (k2 * 4 + lg) ^ (rowa & 7);
                af[i] = *(const bf16x8_t*)&As[cur][rowa * 64 + ph * 8];
            }
#pragma unroll
            for (int j = 0; j < 4; ++j) {
                int rowb = wc * 64 + j * 16 + lr;
                int ph   = (k2 * 4 + lg) ^ (rowb & 7);
                bfr[j] = *(const bf16x8_t*)&Bs[cur][rowb * 64 + ph * 8];
            }
#pragma unroll
            for (int i = 0; i < 4; ++i)
#pragma unroll
                for (int j = 0; j < 4; ++j)
                    acc[i][j] = MFMA16(af[i], bfr[j], acc[i][j]);
        }

        if (kt < 7) {
            asm volatile("s_waitcnt lgkmcnt(0)" ::: "memory");
            __builtin_amdgcn_sched_barrier(0);
            __builtin_amdgcn_s_barrier();
            __builtin_amdgcn_sched_barrier(0);
        }
    }

    float bj[4];
#pragma unroll
    for (int j = 0; j < 4; ++j) bj[j] = bias[n0 + wc * 64 + j * 16 + lr];
#pragma unroll
    for (int i = 0; i < 4; ++i)
#pragma unroll
        for (int j = 0; j < 4; ++j) {
            int col = n0 + wc * 64 + j * 16 + lr;
#pragma unroll
            for (int r = 0; r < 4; ++r) {
                size_t rw = m0 + wr * 64 + i * 16 + lg * 4 + r;
                C[rw * 512 + col] = acc[i][j][r] + bj[j];
            }
        }
}

// ---------------------------------------------------------------------------
extern "C" void kernel_launch(void* const* d_in, const int* in_sizes, int n_in,
                              void* d_out, int out_size, void* d_ws, size_t ws_size,
                              hipStream_t stream) {
    (void)in_sizes; (void)n_in; (void)out_size; (void)ws_size;
    const float* x      = (const float*)d_in[0];
    const float* pe     = (const float*)d_in[1];
    const float* rpe    = (const float*)d_in[2];
    const float* mask   = (const float*)d_in[3];
    const float* qkv_w  = (const float*)d_in[4];
    const float* qkv_b  = (const float*)d_in[5];
    const float* proj_w = (const float*)d_in[6];
    const float* proj_b = (const float*)d_in[7];
    float* out = (float*)d_out;

    char* ws = (char*)d_ws;
    bf16* wqkvb  = (bf16*)ws;                    // 1,572,864 B
    bf16* wprojb = (bf16*)(ws + 1572864);        //   524,288 B
    bf16* ao     = (bf16*)(ws + 2097152);        // 134,217,728 B (ws total 136.3 MB)

    // d_out (256 MB) as scratch, dead before k_proj's final write:
    bf16* xp   = (bf16*)d_out;                         // 134,217,728 B
    bf16* qkvc = (bf16*)((char*)d_out + 134217728);    // 100,663,296 B (chunk)

    k_wprep<<<256, 256, 0, stream>>>(qkv_w, proj_w, wqkvb, wprojb);
    k_xprep<<<4096, 256, 0, stream>>>(x, pe, xp);
    for (int c = 0; c < 4; ++c) {
        k_qkv<<<3072, 256, 0, stream>>>(xp + (size_t)c * 32768 * 512,
                                        wqkvb, qkv_b, qkvc);
        k_attn<<<512, 256, 0, stream>>>(qkvc, rpe, mask, ao, c * 512);
    }
    k_proj<<<4096, 256, 0, stream>>>(ao, wprojb, proj_b, out);
}

// Round 9
// 712.431 us; speedup vs baseline: 1.3957x; 1.1017x over previous
//
#include <hip/hip_runtime.h>
#include <hip/hip_bf16.h>
#include <cstdint>

// Problem: B_=2048 windows, N=64 tokens, C=512, H=16 heads, hd=32, nW=64.
// Pipeline: k_wprep, k_xprep -> 4x { k_qkv (256^2 8-wave GEMM) -> k_attn } -> k_proj.
typedef __bf16 bf16;
typedef __bf16 bf16x8_t __attribute__((ext_vector_type(8)));
typedef __bf16 bf16x4_t __attribute__((ext_vector_type(4)));
typedef float  f32x4_t  __attribute__((ext_vector_type(4)));

#define MFMA16(a, b, c) __builtin_amdgcn_mfma_f32_16x16x32_bf16((a), (b), (c), 0, 0, 0)

__device__ __forceinline__ void gload_lds16(const bf16* g, bf16* l) {
    __builtin_amdgcn_global_load_lds(
        (const __attribute__((address_space(1))) void*)g,
        (__attribute__((address_space(3))) void*)l,
        16, 0, 0);
}

// ---------------------------------------------------------------------------
// Kernel 1: convert weights to bf16 (qkv_w 1536x512, proj_w 512x512)
// ---------------------------------------------------------------------------
__global__ void k_wprep(const float* __restrict__ wq, const float* __restrict__ wp,
                        bf16* __restrict__ wqb, bf16* __restrict__ wpb) {
    int t = blockIdx.x * 256 + threadIdx.x;
    int stride = gridDim.x * 256;
    for (int i = t; i < 196608; i += stride) {
        float4 v = ((const float4*)wq)[i];
        bf16x4_t o; o[0]=(bf16)v.x; o[1]=(bf16)v.y; o[2]=(bf16)v.z; o[3]=(bf16)v.w;
        ((bf16x4_t*)wqb)[i] = o;
    }
    for (int i = t; i < 65536; i += stride) {
        float4 v = ((const float4*)wp)[i];
        bf16x4_t o; o[0]=(bf16)v.x; o[1]=(bf16)v.y; o[2]=(bf16)v.z; o[3]=(bf16)v.w;
        ((bf16x4_t*)wpb)[i] = o;
    }
}

// ---------------------------------------------------------------------------
// Kernel 2: xp[131072][512] = bf16(x + pe)  (one shot, memory-bound)
// ---------------------------------------------------------------------------
__global__ void k_xprep(const float* __restrict__ x, const float* __restrict__ pe,
                        bf16* __restrict__ xp) {
    int t = blockIdx.x * 256 + threadIdx.x;
    int stride = gridDim.x * 256;
    for (int i = t; i < 8388608; i += stride) {
        int row = i >> 6;
        int g   = (i & 63) * 8;
        const float* xr = x  + ((size_t)row << 9) + g;
        const float* pr = pe + ((size_t)(row & 63) << 9) + g;
        float4 x0 = *(const float4*)(xr);
        float4 x1 = *(const float4*)(xr + 4);
        float4 p0 = *(const float4*)(pr);
        float4 p1 = *(const float4*)(pr + 4);
        bf16x8_t v;
        v[0]=(bf16)(x0.x+p0.x); v[1]=(bf16)(x0.y+p0.y);
        v[2]=(bf16)(x0.z+p0.z); v[3]=(bf16)(x0.w+p0.w);
        v[4]=(bf16)(x1.x+p1.x); v[5]=(bf16)(x1.y+p1.y);
        v[6]=(bf16)(x1.z+p1.z); v[7]=(bf16)(x1.w+p1.w);
        *(bf16x8_t*)(xp + (size_t)i * 8) = v;
    }
}

// ---------------------------------------------------------------------------
// Kernel 3: QKV GEMM over one 32768-row chunk. 256x256 tile, BK=64, 8 waves.
// r8-proven skeleton scaled 2x: pure gload_lds staging (8/wave/iter, both
// operands XOR-swizzled ph=(k2*4+lg)^(row&7)), exact vmcnt(8), raw barriers
// + sched_barrier fences. 64 MFMA/wave/iter (2x intensity per staged byte).
// LDS 128 KB -> 1 block/CU. Output head-major: [3][16][512][64][32] bf16.
// ---------------------------------------------------------------------------
__global__ __launch_bounds__(512, 2) void k_qkv(
    const bf16*  __restrict__ A,     // chunk xp: (32768, 512) bf16
    const bf16*  __restrict__ Bw,    // (1536, 512) bf16
    const float* __restrict__ bias,  // (1536,) f32
    bf16* __restrict__ Cq)           // chunk out, head-major (100.7 MB)
{
    __shared__ bf16 As[2][256 * 64]; // linear, XOR-swizzled pieces (32 KB each)
    __shared__ bf16 Bs[2][256 * 64];
    // LDS 131,072 B -> 1 block/CU

    const int tid  = threadIdx.x;
    const int lane = tid & 63;
    const int wave = tid >> 6;
    const int lr = lane & 15, lg = lane >> 4;
    const int wr = wave >> 2;            // 0..1 : 128-row half
    const int wc = wave & 3;             // 0..3 : 64-col quarter
    const int bid = blockIdx.x;          // 0..767 (= 8 * 96) per chunk
    const int wg  = (bid & 7) * 96 + (bid >> 3);  // XCD-contiguous
    const int mb  = wg / 6, nb = wg - mb * 6;     // 128 x 6
    const size_t m0 = (size_t)mb * 256;
    const int n0 = nb * 256;

    f32x4_t acc[8][4] = {};

    auto stage = [&](int kt, int buf) {
        const int k0 = kt * 64;
#pragma unroll
        for (int ii = 0; ii < 4; ++ii) {
            int instr = wave * 4 + ii;           // 0..31, 1KB each (8 rows)
            int r  = instr * 8 + (lane >> 3);    // tile row 0..255
            int gp = (lane & 7) ^ (r & 7);       // pre-swizzled source piece
            gload_lds16(A  + (m0 + r) * 512 + k0 + gp * 8, &As[buf][instr * 512]);
            gload_lds16(Bw + (size_t)(n0 + r) * 512 + k0 + gp * 8, &Bs[buf][instr * 512]);
        }
    };

    stage(0, 0);

    for (int kt = 0; kt < 8; ++kt) {
        const int cur = kt & 1;
        if (kt < 7) {
            stage(kt + 1, cur ^ 1);
            asm volatile("s_waitcnt vmcnt(8) lgkmcnt(0)" ::: "memory");
        } else {
            asm volatile("s_waitcnt vmcnt(0) lgkmcnt(0)" ::: "memory");
        }
        __builtin_amdgcn_sched_barrier(0);
        __builtin_amdgcn_s_barrier();            // buf[cur] staged, all waves
        __builtin_amdgcn_sched_barrier(0);

#pragma unroll
        for (int k2 = 0; k2 < 2; ++k2) {
            bf16x8_t af[8], bfr[4];
#pragma unroll
            for (int i = 0; i < 8; ++i) {
                int rowa = wr * 128 + i * 16 + lr;
                int ph   = (k2 * 4 + lg) ^ (rowa & 7);
                af[i] = *(const bf16x8_t*)&As[cur][rowa * 64 + ph * 8];
            }
#pragma unroll
            for (int j = 0; j < 4; ++j) {
                int rowb = n0 ? 0 : 0, dummy = 0; (void)dummy;
                int rb   = wc * 64 + j * 16 + lr;
                int ph   = (k2 * 4 + lg) ^ (rb & 7);
                bfr[j] = *(const bf16x8_t*)&Bs[cur][rb * 64 + ph * 8];
            }
#pragma unroll
            for (int i = 0; i < 8; ++i)
#pragma unroll
                for (int j = 0; j < 4; ++j)
                    acc[i][j] = MFMA16(af[i], bfr[j], acc[i][j]);
        }

        if (kt < 7) {
            asm volatile("s_waitcnt lgkmcnt(0)" ::: "memory");  // my reads retired
            __builtin_amdgcn_sched_barrier(0);
            __builtin_amdgcn_s_barrier();        // all reads done -> overwrite ok
            __builtin_amdgcn_sched_barrier(0);
        }
    }

    // ---- epilogue: bias + head-major store ----------------------------------
    float bj[4];
#pragma unroll
    for (int j = 0; j < 4; ++j) bj[j] = bias[n0 + wc * 64 + j * 16 + lr];
#pragma unroll
    for (int i = 0; i < 8; ++i)
#pragma unroll
        for (int j = 0; j < 4; ++j) {
            int col   = n0 + wc * 64 + j * 16 + lr;    // 0..1535
            int which = col >> 9;
            int h     = (col >> 5) & 15;
            int d     = col & 31;
            bf16* base = Cq + (size_t)(which * 16 + h) * (512 * 2048);
#pragma unroll
            for (int r = 0; r < 4; ++r) {
                int mrow = (int)m0 + wr * 128 + i * 16 + lg * 4 + r;
                int win = mrow >> 6, tok = mrow & 63;  // win 0..511 local
                base[(size_t)win * 2048 + tok * 32 + d] = (bf16)(acc[i][j][r] + bj[j]);
            }
        }
}

// ---------------------------------------------------------------------------
// Kernel 4: window attention over one 512-window chunk. BARRIER-FREE:
// each wave owns (window, 4 heads), private vts/ps LDS. Head-major input.
// ---------------------------------------------------------------------------
__global__ __launch_bounds__(256, 2) void k_attn(
    const bf16*  __restrict__ qkv,   // chunk head-major [3][16][512][64][32]
    const float* __restrict__ rpe,   // (16,64,64) f32
    const float* __restrict__ mask,  // (64,64,64) f32
    bf16* __restrict__ ao,           // (2048,64,512) bf16 (global rows)
    int winbase)                     // chunk * 512
{
    __shared__ bf16 vts[4][32 * 72]; // per-wave v^T [32 d][64 tok pad 72]
    __shared__ bf16 ps[4][64 * 72];  // per-wave P   [64 q ][64 tok pad 72]

    const int tid  = threadIdx.x;
    const int lane = tid & 63;
    const int wave = tid >> 6;
    const int lr   = lane & 15;
    const int lg   = lane >> 4;
    const int bw   = blockIdx.x;          // local window 0..511
    const int gw   = winbase + bw;        // global window
    const int wi   = gw & 63;             // mask index
    const float* mp = mask + (size_t)wi * 4096;
    bf16* pvt = &vts[wave][0];
    bf16* pps = &ps[wave][0];

    const float SCALE = 0.17677669529663687f;  // 32^-0.5

    for (int hh = 0; hh < 4; ++hh) {
        const int h  = wave * 4 + hh;
        const float* rp = rpe + (size_t)h * 4096;
        const bf16* qb = qkv + ((size_t)(h)      * 512 + bw) * 2048;
        const bf16* kb = qkv + ((size_t)(16 + h) * 512 + bw) * 2048;
        const bf16* vb = qkv + ((size_t)(32 + h) * 512 + bw) * 2048;

        bf16x8_t qf[4], kf[4];
#pragma unroll
        for (int t = 0; t < 4; ++t) {
            qf[t] = *(const bf16x8_t*)(qb + (t * 16 + lr) * 32 + lg * 8);
            kf[t] = *(const bf16x8_t*)(kb + (t * 16 + lr) * 32 + lg * 8);
        }
#pragma unroll
        for (int j = 0; j < 4; ++j) {
            bf16x8_t vr = *(const bf16x8_t*)(vb + (j * 16 + (lane >> 2)) * 32 + (lane & 3) * 8);
#pragma unroll
            for (int i = 0; i < 8; ++i)
                pvt[((lane & 3) * 8 + i) * 72 + j * 16 + (lane >> 2)] = vr[i];
        }

        float sminv[4][4];
#pragma unroll
        for (int mt = 0; mt < 4; ++mt) {
            f32x4_t s[4];
            f32x4_t zero = {};
#pragma unroll
            for (int nt = 0; nt < 4; ++nt)
                s[nt] = MFMA16(qf[mt], kf[nt], zero);
            float rm[4][4];
#pragma unroll
            for (int nt = 0; nt < 4; ++nt) {
                int col = nt * 16 + lr;
#pragma unroll
                for (int r = 0; r < 4; ++r) {
                    int rrow = mt * 16 + lg * 4 + r;
                    rm[nt][r] = rp[rrow * 64 + col] + mp[rrow * 64 + col];
                }
            }
            float mx[4] = {-1e30f, -1e30f, -1e30f, -1e30f};
#pragma unroll
            for (int nt = 0; nt < 4; ++nt)
#pragma unroll
                for (int r = 0; r < 4; ++r) {
                    float tv = s[nt][r] * SCALE + rm[nt][r];
                    s[nt][r] = tv;
                    mx[r] = fmaxf(mx[r], tv);
                }
#pragma unroll
            for (int r = 0; r < 4; ++r) {
                float m = mx[r];
                m = fmaxf(m, __shfl_xor(m, 1));
                m = fmaxf(m, __shfl_xor(m, 2));
                m = fmaxf(m, __shfl_xor(m, 4));
                m = fmaxf(m, __shfl_xor(m, 8));
                mx[r] = m;
            }
            float sm[4] = {0.f, 0.f, 0.f, 0.f};
#pragma unroll
            for (int nt = 0; nt < 4; ++nt)
#pragma unroll
                for (int r = 0; r < 4; ++r) {
                    float e = __expf(s[nt][r] - mx[r]);
                    s[nt][r] = e;
                    sm[r] += e;
                }
#pragma unroll
            for (int r = 0; r < 4; ++r) {
                float ssum = sm[r];
                ssum += __shfl_xor(ssum, 1);
                ssum += __shfl_xor(ssum, 2);
                ssum += __shfl_xor(ssum, 4);
                ssum += __shfl_xor(ssum, 8);
                sminv[mt][r] = 1.0f / ssum;
            }
#pragma unroll
            for (int nt = 0; nt < 4; ++nt)
#pragma unroll
                for (int r = 0; r < 4; ++r)
                    pps[(mt * 16 + lg * 4 + r) * 72 + nt * 16 + lr] = (bf16)s[nt][r];
        }

#pragma unroll
        for (int mt = 0; mt < 4; ++mt) {
            f32x4_t o[2] = {};
#pragma unroll
            for (int ks = 0; ks < 2; ++ks) {
                bf16x8_t pa = *(const bf16x8_t*)&pps[(mt * 16 + lr) * 72 + ks * 32 + lg * 8];
#pragma unroll
                for (int jd = 0; jd < 2; ++jd) {
                    bf16x8_t bv = *(const bf16x8_t*)&pvt[(jd * 16 + lr) * 72 + ks * 32 + lg * 8];
                    o[jd] = MFMA16(pa, bv, o[jd]);
                }
            }
#pragma unroll
            for (int jd = 0; jd < 2; ++jd)
#pragma unroll
                for (int r = 0; r < 4; ++r) {
                    size_t rrow = (size_t)gw * 64 + mt * 16 + lg * 4 + r;
                    ao[rrow * 512 + h * 32 + jd * 16 + lr] = (bf16)(o[jd][r] * sminv[mt][r]);
                }
        }
    }
}

// ---------------------------------------------------------------------------
// Kernel 5: proj GEMM, same 256^2 8-wave skeleton. out = ao@proj_w^T + bias.
// ---------------------------------------------------------------------------
__global__ __launch_bounds__(512, 2) void k_proj(
    const bf16* __restrict__ A, const bf16* __restrict__ Bw,
    const float* __restrict__ bias, float* __restrict__ C)
{
    __shared__ bf16 As[2][256 * 64];
    __shared__ bf16 Bs[2][256 * 64];

    const int tid  = threadIdx.x;
    const int lane = tid & 63;
    const int wave = tid >> 6;
    const int lr = lane & 15, lg = lane >> 4;
    const int wr = wave >> 2, wc = wave & 3;
    const int bid = blockIdx.x;                  // 0..1023 (= 8 * 128)
    const int wg  = (bid & 7) * 128 + (bid >> 3);
    const int mb = wg >> 1, nb = wg & 1;         // 512 x 2
    const size_t m0 = (size_t)mb * 256;
    const int n0 = nb * 256;

    f32x4_t acc[8][4] = {};

    auto stage = [&](int kt, int buf) {
        const int k0 = kt * 64;
#pragma unroll
        for (int ii = 0; ii < 4; ++ii) {
            int instr = wave * 4 + ii;
            int r  = instr * 8 + (lane >> 3);
            int gp = (lane & 7) ^ (r & 7);
            gload_lds16(A  + (m0 + r) * 512 + k0 + gp * 8, &As[buf][instr * 512]);
            gload_lds16(Bw + (size_t)(n0 + r) * 512 + k0 + gp * 8, &Bs[buf][instr * 512]);
        }
    };

    stage(0, 0);

    for (int kt = 0; kt < 8; ++kt) {
        const int cur = kt & 1;
        if (kt < 7) {
            stage(kt + 1, cur ^ 1);
            asm volatile("s_waitcnt vmcnt(8) lgkmcnt(0)" ::: "memory");
        } else {
            asm volatile("s_waitcnt vmcnt(0) lgkmcnt(0)" ::: "memory");
        }
        __builtin_amdgcn_sched_barrier(0);
        __builtin_amdgcn_s_barrier();
        __builtin_amdgcn_sched_barrier(0);

#pragma unroll
        for (int k2 = 0; k2 < 2; ++k2) {
            bf16x8_t af[8], bfr[4];
#pragma unroll
            for (int i = 0; i < 8; ++i) {
                int rowa = wr * 128 + i * 16 + lr;
                int ph   = (k2 * 4 + lg) ^ (rowa & 7);
                af[i] = *(const bf16x8_t*)&As[cur][rowa * 64 + ph * 8];
            }
#pragma unroll
            for (int j = 0; j < 4; ++j) {
                int rb = wc * 64 + j * 16 + lr;
                int ph = (k2 * 4 + lg) ^ (rb & 7);
                bfr[j] = *(const bf16x8_t*)&Bs[cur][rb * 64 + ph * 8];
            }
#pragma unroll
            for (int i = 0; i < 8; ++i)
#pragma unroll
                for (int j = 0; j < 4; ++j)
                    acc[i][j] = MFMA16(af[i], bfr[j], acc[i][j]);
        }

        if (kt < 7) {
            asm volatile("s_waitcnt lgkmcnt(0)" ::: "memory");
            __builtin_amdgcn_sched_barrier(0);
            __builtin_amdgcn_s_barrier();
            __builtin_amdgcn_sched_barrier(0);
        }
    }

    float bj[4];
#pragma unroll
    for (int j = 0; j < 4; ++j) bj[j] = bias[n0 + wc * 64 + j * 16 + lr];
#pragma unroll
    for (int i = 0; i < 8; ++i)
#pragma unroll
        for (int j = 0; j < 4; ++j) {
            int col = n0 + wc * 64 + j * 16 + lr;
#pragma unroll
            for (int r = 0; r < 4; ++r) {
                size_t rw = m0 + wr * 128 + i * 16 + lg * 4 + r;
                C[rw * 512 + col] = acc[i][j][r] + bj[j];
            }
        }
}

// ---------------------------------------------------------------------------
extern "C" void kernel_launch(void* const* d_in, const int* in_sizes, int n_in,
                              void* d_out, int out_size, void* d_ws, size_t ws_size,
                              hipStream_t stream) {
    (void)in_sizes; (void)n_in; (void)out_size; (void)ws_size;
    const float* x      = (const float*)d_in[0];
    const float* pe     = (const float*)d_in[1];
    const float* rpe    = (const float*)d_in[2];
    const float* mask   = (const float*)d_in[3];
    const float* qkv_w  = (const float*)d_in[4];
    const float* qkv_b  = (const float*)d_in[5];
    const float* proj_w = (const float*)d_in[6];
    const float* proj_b = (const float*)d_in[7];
    float* out = (float*)d_out;

    char* ws = (char*)d_ws;
    bf16* wqkvb  = (bf16*)ws;                    // 1,572,864 B
    bf16* wprojb = (bf16*)(ws + 1572864);        //   524,288 B
    bf16* ao     = (bf16*)(ws + 2097152);        // 134,217,728 B (ws total 136.3 MB)

    // d_out (256 MB) as scratch, dead before k_proj's final write:
    bf16* xp   = (bf16*)d_out;                         // 134,217,728 B
    bf16* qkvc = (bf16*)((char*)d_out + 134217728);    // 100,663,296 B (chunk)

    k_wprep<<<256, 256, 0, stream>>>(qkv_w, proj_w, wqkvb, wprojb);
    k_xprep<<<4096, 256, 0, stream>>>(x, pe, xp);
    for (int c = 0; c < 4; ++c) {
        k_qkv<<<768, 512, 0, stream>>>(xp + (size_t)c * 32768 * 512,
                                       wqkvb, qkv_b, qkvc);
        k_attn<<<512, 256, 0, stream>>>(qkvc, rpe, mask, ao, c * 512);
    }
    k_proj<<<1024, 512, 0, stream>>>(ao, wprojb, proj_b, out);
}